// Round 11
// baseline (807.101 us; speedup 1.0000x reference)
//
#include <hip/hip_runtime.h>
#include <hip/hip_bf16.h>

#define BS_   256
#define NOPS_ 2000
#define NJ_   50
#define NM_   40
#define E_    128
#define H_    128
#define NCOL_ 2001   // 1 + 50*40

typedef _Float16 f16;
using f16x8 = __attribute__((ext_vector_type(8))) _Float16;
using f16x4 = __attribute__((ext_vector_type(4))) _Float16;
using f32x4 = __attribute__((ext_vector_type(4))) float;

// ---------------------------------------------------------------------------
// MEASUREMENT ROUND: R10 kernel body, repeated nrep (=16) times inside the
// kernel (runtime arg -> not compile-time removable; idempotent; barrier
// between reps). Purpose: (a) body time = (dur - 37.4)/15, (b) kernel becomes
// long enough to appear in top-5 rocprof dispatches with full counters.
// ---------------------------------------------------------------------------
__global__ __launch_bounds__(512, 2) void fjsp_fused(
    const float* __restrict__ ops_emb,
    const float* __restrict__ ma_emb,
    const int*   __restrict__ next_op,
    const int*   __restrict__ amask,
    const float* __restrict__ dummy,
    const float* __restrict__ W1,
    const float* __restrict__ b1,
    const float* __restrict__ W2,
    const float* __restrict__ b2,
    const float* __restrict__ W3,
    const float* __restrict__ b3,
    float* __restrict__ out,
    int nrep)
{
  const int b    = blockIdx.x;
  const int tid  = threadIdx.x;
  const int lane = tid & 63;
  const int wave = tid >> 6;
  const int g    = lane >> 4;   // 0..3
  const int lr   = lane & 15;   // 0..15

  __shared__ __align__(16) f16 Wlds[384][132];           // 101.4 KB
  __shared__ __align__(16) f16 fragL[32 * 64 * 8];       // 32 KB
  __shared__ __align__(16) f16 jpL[51][132];             // 13.5 KB
  __shared__ __align__(16) f16 mpL[41][132];             // 10.8 KB

  for (int rep = 0; rep < nrep; ++rep) {

  // ========== phase 0: coalesced weight staging (all 512 threads) ==========
  #pragma unroll 4
  for (int idx = tid; idx < 384 * 32; idx += 512) {
    const int row = idx >> 5, c4 = (idx & 31) * 4;
    const float* src = (row < 256) ? (W1 + (size_t)row * H_ + c4)
                                   : (W2 + (size_t)(row - 256) * H_ + c4);
    const float4 v = *reinterpret_cast<const float4*>(src);
    f16x4 h; h[0] = (f16)v.x; h[1] = (f16)v.y; h[2] = (f16)v.z; h[3] = (f16)v.w;
    *reinterpret_cast<f16x4*>(&Wlds[row][c4]) = h;
  }
  __syncthreads();

  // ========================= phase 1 =========================
  if (wave < 4) {
    const bool isJ   = (wave < 2);
    const int  rbase = isJ ? 0 : 128;
    f16x8 wfr[4][8];
    #pragma unroll
    for (int f = 0; f < 4; ++f) {
      #pragma unroll
      for (int c = 0; c < 8; ++c) {
        f16x8 bb;
        #pragma unroll
        for (int i = 0; i < 8; ++i)
          bb[i] = Wlds[rbase + 32 * f + 8 * g + i][16 * c + lr];
        wfr[f][c] = bb;
      }
    }
    float b1r[8];
    #pragma unroll
    for (int c = 0; c < 8; ++c) b1r[c] = isJ ? 0.f : b1[16 * c + lr];

    const int t0 = (wave == 0) ? 0 : (wave == 1) ? 2 : (wave == 2) ? 0 : 2;
    const int nt = (wave == 3) ? 1 : 2;
    for (int q = 0; q < nt; ++q) {
      const int r0 = (t0 + q) * 16;
      const float* src;
      if (isJ) {
        int jr = r0 + lr; if (jr > 50) jr = 50;
        src = (jr == 50) ? dummy
                         : ops_emb + ((size_t)b * NOPS_ + next_op[b * NJ_ + jr]) * E_;
      } else {
        int mr = r0 + lr; if (mr > 40) mr = 40;
        src = (mr == 40) ? (dummy + E_)
                         : ma_emb + ((size_t)b * NM_ + mr) * E_;
      }
      const float4* ep = reinterpret_cast<const float4*>(src);
      f16x8 af[4];
      #pragma unroll
      for (int f = 0; f < 4; ++f) {
        const float4 v0 = ep[8 * f + 2 * g];
        const float4 v1 = ep[8 * f + 2 * g + 1];
        f16x8 a;
        a[0] = (f16)v0.x; a[1] = (f16)v0.y; a[2] = (f16)v0.z; a[3] = (f16)v0.w;
        a[4] = (f16)v1.x; a[5] = (f16)v1.y; a[6] = (f16)v1.z; a[7] = (f16)v1.w;
        af[f] = a;
      }
      f32x4 acc[8];
      #pragma unroll
      for (int c = 0; c < 8; ++c) acc[c] = f32x4{b1r[c], b1r[c], b1r[c], b1r[c]};
      #pragma unroll
      for (int f = 0; f < 4; ++f)
        #pragma unroll
        for (int c = 0; c < 8; ++c)
          acc[c] = __builtin_amdgcn_mfma_f32_16x16x32_f16(af[f], wfr[f][c], acc[c], 0, 0, 0);
      #pragma unroll
      for (int c = 0; c < 8; ++c) {
        const int col = 16 * c + lr;
        #pragma unroll
        for (int i = 0; i < 4; ++i) {
          const int row = r0 + 4 * g + i;
          if (isJ) { if (row < 51) jpL[row][col] = (f16)acc[c][i]; }
          else     { if (row < 41) mpL[row][col] = (f16)acc[c][i]; }
        }
      }
    }
  } else if (wave < 7) {
    for (int t = wave - 4; t < 32; t += 3) {
      const int f = t >> 3, c = t & 7;
      f16x8 bb;
      #pragma unroll
      for (int i = 0; i < 8; ++i)
        bb[i] = Wlds[256 + 32 * f + 8 * g + i][16 * c + lr];
      *reinterpret_cast<f16x8*>(&fragL[((size_t)t * 64 + lane) * 8]) = bb;
    }
  } else {
    const int* mrow = amask + (size_t)b * NCOL_;
    float* __restrict__ orow = out + (size_t)BS_ * NCOL_ + (size_t)b * NCOL_;
    #pragma unroll 4
    for (int i = lane; i < NCOL_; i += 64) orow[i] = mrow[i] != 0 ? 1.0f : 0.0f;
  }
  __syncthreads();

  // ========================= phase 2 =========================
  f16x8 w2f[4][8];
  #pragma unroll
  for (int f = 0; f < 4; ++f)
    #pragma unroll
    for (int c = 0; c < 8; ++c)
      w2f[f][c] = *reinterpret_cast<const f16x8*>(
          &fragL[((size_t)(f * 8 + c) * 64 + lane) * 8]);
  f16x4 b2h[8];
  float4 w3v[8];
  #pragma unroll
  for (int c = 0; c < 8; ++c) {
    const float4 bv = *reinterpret_cast<const float4*>(b2 + 16 * c + 4 * g);
    f16x4 hh; hh[0] = (f16)bv.x; hh[1] = (f16)bv.y; hh[2] = (f16)bv.z; hh[3] = (f16)bv.w;
    b2h[c] = hh;
    w3v[c] = *reinterpret_cast<const float4*>(W3 + 16 * c + 4 * g);
  }
  const float bias3 = b3[0];
  float* __restrict__ outb = out + (size_t)b * NCOL_;

  #pragma unroll 1
  for (int t = wave; t < 126; t += 8) {
    const int p  = t * 16 + lr;               // pair index, 2000 = noop
    const int p2 = (p < 2000) ? p : 2000;
    int j, m;
    if (p2 == 2000) { j = 50; m = 40; }
    else            { j = p2 / 40; m = p2 - j * 40; }
    f16x8 afr[4];
    #pragma unroll
    for (int f = 0; f < 4; ++f) {
      const f16x4 jlo = *reinterpret_cast<const f16x4*>(&jpL[j][32 * f + 8 * g]);
      const f16x4 jhi = *reinterpret_cast<const f16x4*>(&jpL[j][32 * f + 8 * g + 4]);
      const f16x4 mlo = *reinterpret_cast<const f16x4*>(&mpL[m][32 * f + 8 * g]);
      const f16x4 mhi = *reinterpret_cast<const f16x4*>(&mpL[m][32 * f + 8 * g + 4]);
      const f16x4 z   = {(f16)0.f, (f16)0.f, (f16)0.f, (f16)0.f};
      const f16x4 slo = __builtin_elementwise_max(jlo + mlo, z);
      const f16x4 shi = __builtin_elementwise_max(jhi + mhi, z);
      afr[f] = __builtin_shufflevector(slo, shi, 0, 1, 2, 3, 4, 5, 6, 7);
    }
    f32x4 acc[8];
    #pragma unroll
    for (int c = 0; c < 8; ++c)
      acc[c] = f32x4{(float)b2h[c][0], (float)b2h[c][1],
                     (float)b2h[c][2], (float)b2h[c][3]};
    #pragma unroll
    for (int f = 0; f < 4; ++f)
      #pragma unroll
      for (int c = 0; c < 8; ++c)
        acc[c] = __builtin_amdgcn_mfma_f32_16x16x32_f16(w2f[f][c], afr[f], acc[c], 0, 0, 0);
    float pv = 0.f;
    #pragma unroll
    for (int c = 0; c < 8; ++c) {
      pv = fmaf(fmaxf(acc[c][0], 0.f), w3v[c].x, pv);
      pv = fmaf(fmaxf(acc[c][1], 0.f), w3v[c].y, pv);
      pv = fmaf(fmaxf(acc[c][2], 0.f), w3v[c].z, pv);
      pv = fmaf(fmaxf(acc[c][3], 0.f), w3v[c].w, pv);
    }
    pv += __shfl_xor(pv, 16);
    pv += __shfl_xor(pv, 32);
    if (g == 0 && p <= 2000)
      outb[(p == 2000) ? 0 : (p + 1)] = pv + bias3;
  }

  __syncthreads();   // isolate reps (rep+1 phase-0/1 writes vs rep phase-2 reads)
  }  // rep loop
}

extern "C" void kernel_launch(void* const* d_in, const int* in_sizes, int n_in,
                              void* d_out, int out_size, void* d_ws, size_t ws_size,
                              hipStream_t stream) {
  (void)in_sizes; (void)n_in; (void)d_ws; (void)ws_size; (void)out_size;
  fjsp_fused<<<dim3(BS_), dim3(512), 0, stream>>>(
      (const float*)d_in[0],   // ops_emb
      (const float*)d_in[1],   // ma_emb
      (const int*)d_in[2],     // next_op
      (const int*)d_in[3],     // action_mask (bool -> int32)
      (const float*)d_in[4],   // dummy
      (const float*)d_in[5],   // W1
      (const float*)d_in[6],   // b1
      (const float*)d_in[7],   // W2
      (const float*)d_in[8],   // b2
      (const float*)d_in[9],   // W3
      (const float*)d_in[10],  // b3
      (float*)d_out,
      16);                     // nrep (runtime, measurement)
}

// Round 12
// 36.830 us; speedup vs baseline: 21.9143x; 21.9143x over previous
//
#include <hip/hip_runtime.h>
#include <hip/hip_bf16.h>

#define BS_   256
#define NOPS_ 2000
#define NJ_   50
#define NM_   40
#define E_    128
#define H_    128
#define NCOL_ 2001   // 1 + 50*40

typedef _Float16 f16;
using f16x8 = __attribute__((ext_vector_type(8))) _Float16;
using f16x4 = __attribute__((ext_vector_type(4))) _Float16;
using f32x4 = __attribute__((ext_vector_type(4))) float;

// ---------------------------------------------------------------------------
// R12 = R10 body + register-pressure fix.
// KEY CHANGE: amdgpu_waves_per_eu(2,2) pins occupancy to exactly 2 waves/EU
// (the 8-wave block's residency), giving the allocator the full 256-VGPR
// budget. R11 counters showed VGPR_Count=128 with ~240 live values -> ~100
// spilled regs -> scratch traffic (FETCH 439MB/WRITE 640MB, 10x logical) and
// all pipes <25% busy. That spill was the structure-invariant ~20us.
// ---------------------------------------------------------------------------
__global__ __launch_bounds__(512)
__attribute__((amdgpu_waves_per_eu(2, 2)))
void fjsp_fused(
    const float* __restrict__ ops_emb,
    const float* __restrict__ ma_emb,
    const int*   __restrict__ next_op,
    const int*   __restrict__ amask,
    const float* __restrict__ dummy,
    const float* __restrict__ W1,
    const float* __restrict__ b1,
    const float* __restrict__ W2,
    const float* __restrict__ b2,
    const float* __restrict__ W3,
    const float* __restrict__ b3,
    float* __restrict__ out)
{
  const int b    = blockIdx.x;
  const int tid  = threadIdx.x;
  const int lane = tid & 63;
  const int wave = tid >> 6;
  const int g    = lane >> 4;   // 0..3
  const int lr   = lane & 15;   // 0..15

  __shared__ __align__(16) f16 Wlds[384][132];           // 101.4 KB
  __shared__ __align__(16) f16 fragL[32 * 64 * 8];       // 32 KB
  __shared__ __align__(16) f16 jpL[51][132];             // 13.5 KB
  __shared__ __align__(16) f16 mpL[41][132];             // 10.8 KB

  // ========== phase 0: coalesced weight staging (all 512 threads) ==========
  #pragma unroll 4
  for (int idx = tid; idx < 384 * 32; idx += 512) {
    const int row = idx >> 5, c4 = (idx & 31) * 4;
    const float* src = (row < 256) ? (W1 + (size_t)row * H_ + c4)
                                   : (W2 + (size_t)(row - 256) * H_ + c4);
    const float4 v = *reinterpret_cast<const float4*>(src);
    f16x4 h; h[0] = (f16)v.x; h[1] = (f16)v.y; h[2] = (f16)v.z; h[3] = (f16)v.w;
    *reinterpret_cast<f16x4*>(&Wlds[row][c4]) = h;
  }
  __syncthreads();

  // ========================= phase 1 =========================
  if (wave < 4) {
    const bool isJ   = (wave < 2);
    const int  rbase = isJ ? 0 : 128;
    f16x8 wfr[4][8];
    #pragma unroll
    for (int f = 0; f < 4; ++f) {
      #pragma unroll
      for (int c = 0; c < 8; ++c) {
        f16x8 bb;
        #pragma unroll
        for (int i = 0; i < 8; ++i)
          bb[i] = Wlds[rbase + 32 * f + 8 * g + i][16 * c + lr];
        wfr[f][c] = bb;
      }
    }
    float b1r[8];
    #pragma unroll
    for (int c = 0; c < 8; ++c) b1r[c] = isJ ? 0.f : b1[16 * c + lr];

    const int t0 = (wave == 0) ? 0 : (wave == 1) ? 2 : (wave == 2) ? 0 : 2;
    const int nt = (wave == 3) ? 1 : 2;
    for (int q = 0; q < nt; ++q) {
      const int r0 = (t0 + q) * 16;
      const float* src;
      if (isJ) {
        int jr = r0 + lr; if (jr > 50) jr = 50;
        src = (jr == 50) ? dummy
                         : ops_emb + ((size_t)b * NOPS_ + next_op[b * NJ_ + jr]) * E_;
      } else {
        int mr = r0 + lr; if (mr > 40) mr = 40;
        src = (mr == 40) ? (dummy + E_)
                         : ma_emb + ((size_t)b * NM_ + mr) * E_;
      }
      const float4* ep = reinterpret_cast<const float4*>(src);
      f16x8 af[4];
      #pragma unroll
      for (int f = 0; f < 4; ++f) {
        const float4 v0 = ep[8 * f + 2 * g];
        const float4 v1 = ep[8 * f + 2 * g + 1];
        f16x8 a;
        a[0] = (f16)v0.x; a[1] = (f16)v0.y; a[2] = (f16)v0.z; a[3] = (f16)v0.w;
        a[4] = (f16)v1.x; a[5] = (f16)v1.y; a[6] = (f16)v1.z; a[7] = (f16)v1.w;
        af[f] = a;
      }
      f32x4 acc[8];
      #pragma unroll
      for (int c = 0; c < 8; ++c) acc[c] = f32x4{b1r[c], b1r[c], b1r[c], b1r[c]};
      #pragma unroll
      for (int f = 0; f < 4; ++f)
        #pragma unroll
        for (int c = 0; c < 8; ++c)
          acc[c] = __builtin_amdgcn_mfma_f32_16x16x32_f16(af[f], wfr[f][c], acc[c], 0, 0, 0);
      #pragma unroll
      for (int c = 0; c < 8; ++c) {
        const int col = 16 * c + lr;
        #pragma unroll
        for (int i = 0; i < 4; ++i) {
          const int row = r0 + 4 * g + i;
          if (isJ) { if (row < 51) jpL[row][col] = (f16)acc[c][i]; }
          else     { if (row < 41) mpL[row][col] = (f16)acc[c][i]; }
        }
      }
    }
  } else if (wave < 7) {
    for (int t = wave - 4; t < 32; t += 3) {
      const int f = t >> 3, c = t & 7;
      f16x8 bb;
      #pragma unroll
      for (int i = 0; i < 8; ++i)
        bb[i] = Wlds[256 + 32 * f + 8 * g + i][16 * c + lr];
      *reinterpret_cast<f16x8*>(&fragL[((size_t)t * 64 + lane) * 8]) = bb;
    }
  } else {
    const int* mrow = amask + (size_t)b * NCOL_;
    float* __restrict__ orow = out + (size_t)BS_ * NCOL_ + (size_t)b * NCOL_;
    #pragma unroll 4
    for (int i = lane; i < NCOL_; i += 64) orow[i] = mrow[i] != 0 ? 1.0f : 0.0f;
  }
  __syncthreads();

  // ========================= phase 2 =========================
  f16x8 w2f[4][8];
  #pragma unroll
  for (int f = 0; f < 4; ++f)
    #pragma unroll
    for (int c = 0; c < 8; ++c)
      w2f[f][c] = *reinterpret_cast<const f16x8*>(
          &fragL[((size_t)(f * 8 + c) * 64 + lane) * 8]);
  f16x4 b2h[8];
  float4 w3v[8];
  #pragma unroll
  for (int c = 0; c < 8; ++c) {
    const float4 bv = *reinterpret_cast<const float4*>(b2 + 16 * c + 4 * g);
    f16x4 hh; hh[0] = (f16)bv.x; hh[1] = (f16)bv.y; hh[2] = (f16)bv.z; hh[3] = (f16)bv.w;
    b2h[c] = hh;
    w3v[c] = *reinterpret_cast<const float4*>(W3 + 16 * c + 4 * g);
  }
  const float bias3 = b3[0];
  float* __restrict__ outb = out + (size_t)b * NCOL_;

  #pragma unroll 1
  for (int t = wave; t < 126; t += 8) {
    const int p  = t * 16 + lr;               // pair index, 2000 = noop
    const int p2 = (p < 2000) ? p : 2000;
    int j, m;
    if (p2 == 2000) { j = 50; m = 40; }
    else            { j = p2 / 40; m = p2 - j * 40; }
    f32x4 acc[8];
    #pragma unroll
    for (int c = 0; c < 8; ++c)
      acc[c] = f32x4{(float)b2h[c][0], (float)b2h[c][1],
                     (float)b2h[c][2], (float)b2h[c][3]};
    // afr built per f INSIDE the loop: live A-frag regs 4 instead of 16
    #pragma unroll
    for (int f = 0; f < 4; ++f) {
      const f16x4 jlo = *reinterpret_cast<const f16x4*>(&jpL[j][32 * f + 8 * g]);
      const f16x4 jhi = *reinterpret_cast<const f16x4*>(&jpL[j][32 * f + 8 * g + 4]);
      const f16x4 mlo = *reinterpret_cast<const f16x4*>(&mpL[m][32 * f + 8 * g]);
      const f16x4 mhi = *reinterpret_cast<const f16x4*>(&mpL[m][32 * f + 8 * g + 4]);
      const f16x4 z   = {(f16)0.f, (f16)0.f, (f16)0.f, (f16)0.f};
      const f16x4 slo = __builtin_elementwise_max(jlo + mlo, z);
      const f16x4 shi = __builtin_elementwise_max(jhi + mhi, z);
      const f16x8 afr = __builtin_shufflevector(slo, shi, 0, 1, 2, 3, 4, 5, 6, 7);
      #pragma unroll
      for (int c = 0; c < 8; ++c)     // SWAPPED: A = W2^T frag, B = h1^T frag
        acc[c] = __builtin_amdgcn_mfma_f32_16x16x32_f16(w2f[f][c], afr, acc[c], 0, 0, 0);
    }
    float pv = 0.f;
    #pragma unroll
    for (int c = 0; c < 8; ++c) {
      pv = fmaf(fmaxf(acc[c][0], 0.f), w3v[c].x, pv);
      pv = fmaf(fmaxf(acc[c][1], 0.f), w3v[c].y, pv);
      pv = fmaf(fmaxf(acc[c][2], 0.f), w3v[c].z, pv);
      pv = fmaf(fmaxf(acc[c][3], 0.f), w3v[c].w, pv);
    }
    pv += __shfl_xor(pv, 16);
    pv += __shfl_xor(pv, 32);
    if (g == 0 && p <= 2000)
      outb[(p == 2000) ? 0 : (p + 1)] = pv + bias3;   // coalesced 16-lane store
  }
}

extern "C" void kernel_launch(void* const* d_in, const int* in_sizes, int n_in,
                              void* d_out, int out_size, void* d_ws, size_t ws_size,
                              hipStream_t stream) {
  (void)in_sizes; (void)n_in; (void)d_ws; (void)ws_size; (void)out_size;
  fjsp_fused<<<dim3(BS_), dim3(512), 0, stream>>>(
      (const float*)d_in[0],   // ops_emb
      (const float*)d_in[1],   // ma_emb
      (const int*)d_in[2],     // next_op
      (const int*)d_in[3],     // action_mask (bool -> int32)
      (const float*)d_in[4],   // dummy
      (const float*)d_in[5],   // W1
      (const float*)d_in[6],   // b1
      (const float*)d_in[7],   // W2
      (const float*)d_in[8],   // b2
      (const float*)d_in[9],   // W3
      (const float*)d_in[10],  // b3
      (float*)d_out);
}